// Round 6
// baseline (7252.679 us; speedup 1.0000x reference)
//
#include <hip/hip_runtime.h>
#include <hip/hip_bf16.h>
#include <stdint.h>

// Persistent-kernel time-skewed acoustic FD: one kernel, 200 windows of
// k=5 steps, DIY grid barrier between windows. Coefficients + own tile
// state live in registers for the whole run; only halos go through global
// (double-buffered). 256 WGs = 256 CUs (co-residency forced via LDS pad).

#define NXd 512
#define NZd 512
#define NTd 1000
#define Sd  2
#define Rd  512
#define C1f 1.125f
#define C2f (-1.0f/24.0f)
#define CVXf 1e-4f              // DT/DX
#define SRC_AMPf 1e-5f          // DT/(DX*DZ)

#define TZ 32
#define TX 64
#define KSTEPS 5
#define NWIN 200
#define Hz 24                   // z-halo >= 4k+4
#define Hx 32                   // x-halo (32 lanes x 4 floats = 128 wide)
#define RLZ 80
#define RLX 128
#define ZB 5                    // z-rows per thread

#define NN  (NZd*NXd)
#define FSZ (Sd*NN)             // floats per field (both shots)
#define BUF_SZ (3*FSZ)          // p,vx,vz one buffer
#define FLAG_OFF (2*BUF_SZ)
#define BAR_OFF  (2*BUF_SZ + 32)            // 64B-aligned barrier area
#define WS_NEED_FLOATS (2*BUF_SZ + 32 + 160)
#define WS_NEED_BYTES ((size_t)WS_NEED_FLOATS * 4)

__device__ __forceinline__ float4 ld4(const float* p) { return *(const float4*)p; }
__device__ __forceinline__ void st4(float* p, float4 v) { *(float4*)p = v; }

// DPP wave shifts (verified round 5): wave_shr:1 (0x138) = value from lane-1,
// wave_shl:1 (0x130) = value from lane+1. bound_ctrl -> 0 at wave edge.
__device__ __forceinline__ float sh_up1(float v) {
    return __int_as_float(__builtin_amdgcn_update_dpp(
        0, __float_as_int(v), 0x138, 0xF, 0xF, true));
}
__device__ __forceinline__ float sh_dn1(float v) {
    return __int_as_float(__builtin_amdgcn_update_dpp(
        0, __float_as_int(v), 0x130, 0xF, 0xF, true));
}

__global__ void detect_k(const uint32_t* __restrict__ vp_raw, int* __restrict__ flag) {
    int lane = threadIdx.x;
    uint32_t u = vp_raw[lane];
    int hb = (u >> 8) & 0xFF;
    int is_exp = (hb == 0x44 || hb == 0x45) ? 1 : 0;
    unsigned long long m = __ballot(is_exp);
    if (lane == 0) *flag = (__popcll(m) >= 48) ? 1 : 0;
}

__device__ __forceinline__ float load_in(const void* p, int i, int bf) {
    return bf ? __bfloat162float(((const __hip_bfloat16*)p)[i])
              : ((const float*)p)[i];
}

// grid barrier: 8 group counters (one per wg&7, 64B apart) -> master -> gen.
// __threadfence (agent) = release (buffer_wbl2) / acquire (buffer_inv) on gfx950.
__device__ __forceinline__ void gbar(unsigned* __restrict__ bar, int wg) {
    __syncthreads();
    if (threadIdx.x == 0) {
        __threadfence();
        unsigned* gcnt = bar + (wg & 7) * 16;
        unsigned* mcnt = bar + 128;
        unsigned* gen  = bar + 144;
        unsigned g = __hip_atomic_load(gen, __ATOMIC_RELAXED, __HIP_MEMORY_SCOPE_AGENT);
        unsigned a = __hip_atomic_fetch_add(gcnt, 1u, __ATOMIC_ACQ_REL, __HIP_MEMORY_SCOPE_AGENT);
        if (a == 31u) {
            __hip_atomic_store(gcnt, 0u, __ATOMIC_RELAXED, __HIP_MEMORY_SCOPE_AGENT);
            unsigned m = __hip_atomic_fetch_add(mcnt, 1u, __ATOMIC_ACQ_REL, __HIP_MEMORY_SCOPE_AGENT);
            if (m == 7u) {
                __hip_atomic_store(mcnt, 0u, __ATOMIC_RELAXED, __HIP_MEMORY_SCOPE_AGENT);
                __hip_atomic_store(gen, g + 1u, __ATOMIC_RELEASE, __HIP_MEMORY_SCOPE_AGENT);
            }
        }
        for (int it = 0; it < 300000; ++it) {   // capped spin: no infinite hang
            if (__hip_atomic_load(gen, __ATOMIC_RELAXED, __HIP_MEMORY_SCOPE_AGENT) != g) break;
            __builtin_amdgcn_s_sleep(2);
        }
        __threadfence();
    }
    __syncthreads();
}

__global__ __launch_bounds__(512, 2) void persist_k(float* __restrict__ ws,
        void* __restrict__ out, const void* __restrict__ vp,
        const void* __restrict__ rho, const void* __restrict__ damp,
        const void* __restrict__ wav,
        const int* __restrict__ sxp, const int* __restrict__ szp,
        const int* __restrict__ rxp, const int* __restrict__ rzp) {
    __shared__ float lp [RLZ*RLX];
    __shared__ float lvz[RLZ*RLX + 1200];   // pad: LDS 86.7KB -> 1 WG/CU forced

    const int tid  = threadIdx.x;
    const int xg   = tid & 31;
    const int zblk = tid >> 5;
    const int zb0  = zblk * ZB;
    const int xo   = xg * 4;

    // XCD-aware tile mapping: wg&7 = XCD -> 4x4 tile macroblock (same
    // spatial block for both shots on one XCD).
    const int wg  = blockIdx.x;
    const int xcd = wg & 7;
    const int ii  = wg >> 3;
    const int s   = ii >> 4;
    const int loc = ii & 15;
    const int tz0 = ((xcd >> 1) * 4 + (loc >> 2)) * TZ;
    const int tx0 = ((xcd & 1) * 4 + (loc & 3)) * TX;
    const int bf  = *(const int*)(ws + FLAG_OFF);
    unsigned* bar = (unsigned*)(ws + BAR_OFF);

    const int rxv = rxp[tid], rzv = rzp[tid];
    const bool own = (rzv >= tz0 && rzv < tz0 + TZ && rxv >= tx0 && rxv < tx0 + TX);
    const int lrcv = (rzv - tz0 + Hz) * RLX + (rxv - tx0 + Hx);
    const int sxv = sxp[s], szv = szp[s];

    // clamped z-neighbor row indices (region edges tolerate garbage)
    const int zPm  = (zb0 - 1 < 0) ? 0 : zb0 - 1;
    const int zPn0 = (zb0 + ZB     > RLZ - 1) ? RLZ - 1 : zb0 + ZB;
    const int zPn1 = (zb0 + ZB + 1 > RLZ - 1) ? RLZ - 1 : zb0 + ZB + 1;
    const int zVm2 = (zb0 - 2 < 0) ? 0 : zb0 - 2;
    const int zVm1 = zPm;
    const int zVn0 = zPn0;

    const float4 zero4 = {0.f, 0.f, 0.f, 0.f};

    // ---- coefficients: loaded ONCE, live in registers for the whole run
    float4 Ca[ZB], Cb[ZB], Cq[ZB];
    #pragma unroll
    for (int r = 0; r < ZB; ++r) {
        int gz = tz0 - Hz + zb0 + r;
        int gx = tx0 - Hx + xo;
        float4 a = zero4, b = zero4, q = zero4;
        if (gz >= 0 && gz < NZd) {
            #pragma unroll
            for (int c = 0; c < 4; ++c) {
                int x = gx + c;
                if (x >= 0 && x < NXd) {
                    int gi = gz * NXd + x;
                    float v  = load_in(vp,  gi, bf);
                    float rr = load_in(rho, gi, bf);
                    float d  = load_in(damp, gi, bf);
                    ((float*)&a)[c] = d;
                    ((float*)&b)[c] = d * (CVXf / rr);
                    ((float*)&q)[c] = d * (CVXf * rr * v * v);
                }
            }
        }
        Ca[r] = a; Cb[r] = b; Cq[r] = q;
    }

    float4 Pv[ZB], Vx[ZB], Vz[ZB];
    #pragma unroll
    for (int r = 0; r < ZB; ++r) { Pv[r] = zero4; Vx[r] = zero4; Vz[r] = zero4; }

    for (int w = 0; w < NWIN; ++w) {
        const float* bR = ws + (w & 1) * BUF_SZ;
        float*       bW = ws + ((w + 1) & 1) * BUF_SZ;
        const float* rp  = bR + s * NN;
        const float* rvx = bR + FSZ + s * NN;
        const float* rvz = bR + 2 * FSZ + s * NN;

        // ---- halo refresh (tile interior stays in registers) + LDS fill
        #pragma unroll
        for (int r = 0; r < ZB; ++r) {
            int z = zb0 + r;
            int gz = tz0 - Hz + z;
            int gx = tx0 - Hx + xo;
            int li = z * RLX + xo;
            bool intile = (z >= Hz && z < Hz + TZ && xo >= Hx && xo < Hx + TX);
            if (!intile) {
                bool in = (gz >= 0) && (gz < NZd) && (gx >= 0) && (gx < NXd);
                if (in) {
                    int gi = gz * NXd + gx;
                    Pv[r] = ld4(rp + gi); Vx[r] = ld4(rvx + gi); Vz[r] = ld4(rvz + gi);
                } else {
                    Pv[r] = zero4; Vx[r] = zero4; Vz[r] = zero4;
                }
            }
            st4(lp + li, Pv[r]);
            st4(lvz + li, Vz[r]);
        }
        __syncthreads();

        for (int j = 0; j < KSTEPS; ++j) {
            const int t = w * KSTEPS + j;
            const float wv = (bf ? __bfloat162float(((const __hip_bfloat16*)wav)[s*NTd + t])
                                 : ((const float*)wav)[s*NTd + t]) * SRC_AMPf;

            const int mV = 4 * (KSTEPS - 1 - j) + 2;
            const int mP = mV - 2;
            const bool actV = (zb0 + ZB > Hz - mV) && (zb0 < Hz + TZ + mV);
            const bool actP = (zb0 + ZB > Hz - mP) && (zb0 < Hz + TZ + mP);

            // ---------- V phase
            if (actV) {
                float4 pPm  = ld4(lp + zPm  * RLX + xo);
                float4 pNx0 = ld4(lp + zPn0 * RLX + xo);
                float4 pNx1 = ld4(lp + zPn1 * RLX + xo);
                #pragma unroll
                for (int r = 0; r < ZB; ++r) {
                    float4 c = Pv[r];
                    float pmw = sh_up1(c.w);
                    float ppx = sh_dn1(c.x);
                    float ppy = sh_dn1(c.y);
                    float4 pzm = (r == 0) ? pPm : Pv[(r == 0) ? 0 : r - 1];
                    float4 pz1 = (r == ZB-1) ? pNx0 : Pv[(r == ZB-1) ? ZB-1 : r + 1];
                    float4 pz2 = (r == ZB-1) ? pNx1 : ((r == ZB-2) ? pNx0 : Pv[(r >= ZB-2) ? ZB-1 : r + 2]);
                    float4 dfx, dfz;
                    dfx.x = C1f*(c.y - c.x) + C2f*(c.z - pmw);
                    dfx.y = C1f*(c.z - c.y) + C2f*(c.w - c.x);
                    dfx.z = C1f*(c.w - c.z) + C2f*(ppx - c.y);
                    dfx.w = C1f*(ppx - c.w) + C2f*(ppy - c.z);
                    dfz.x = C1f*(pz1.x - c.x) + C2f*(pz2.x - pzm.x);
                    dfz.y = C1f*(pz1.y - c.y) + C2f*(pz2.y - pzm.y);
                    dfz.z = C1f*(pz1.z - c.z) + C2f*(pz2.z - pzm.z);
                    dfz.w = C1f*(pz1.w - c.w) + C2f*(pz2.w - pzm.w);
                    Vx[r].x = Ca[r].x*Vx[r].x + Cb[r].x*dfx.x;
                    Vx[r].y = Ca[r].y*Vx[r].y + Cb[r].y*dfx.y;
                    Vx[r].z = Ca[r].z*Vx[r].z + Cb[r].z*dfx.z;
                    Vx[r].w = Ca[r].w*Vx[r].w + Cb[r].w*dfx.w;
                    Vz[r].x = Ca[r].x*Vz[r].x + Cb[r].x*dfz.x;
                    Vz[r].y = Ca[r].y*Vz[r].y + Cb[r].y*dfz.y;
                    Vz[r].z = Ca[r].z*Vz[r].z + Cb[r].z*dfz.z;
                    Vz[r].w = Ca[r].w*Vz[r].w + Cb[r].w*dfz.w;
                }
                st4(lvz + (zb0 + 0) * RLX + xo, Vz[0]);
                st4(lvz + (zb0 + 3) * RLX + xo, Vz[3]);
                st4(lvz + (zb0 + 4) * RLX + xo, Vz[4]);
            }
            __syncthreads();

            // ---------- P phase
            if (actP) {
                float4 vm2 = ld4(lvz + zVm2 * RLX + xo);
                float4 vm1 = ld4(lvz + zVm1 * RLX + xo);
                float4 vn0 = ld4(lvz + zVn0 * RLX + xo);
                #pragma unroll
                for (int r = 0; r < ZB; ++r) {
                    float4 cx = Vx[r], cz = Vz[r];
                    float vmz = sh_up1(cx.z);
                    float vmw = sh_up1(cx.w);
                    float vpx = sh_dn1(cx.x);
                    float4 zm2 = (r == 0) ? vm2 : ((r == 1) ? vm1 : Vz[(r >= 2) ? r - 2 : 0]);
                    float4 zm1 = (r == 0) ? vm1 : Vz[(r == 0) ? 0 : r - 1];
                    float4 zp1 = (r == ZB-1) ? vn0 : Vz[(r == ZB-1) ? ZB-1 : r + 1];
                    float4 dbx, dbz;
                    dbx.x = C1f*(cx.x - vmw)  + C2f*(cx.y - vmz);
                    dbx.y = C1f*(cx.y - cx.x) + C2f*(cx.z - vmw);
                    dbx.z = C1f*(cx.z - cx.y) + C2f*(cx.w - cx.x);
                    dbx.w = C1f*(cx.w - cx.z) + C2f*(vpx  - cx.y);
                    dbz.x = C1f*(cz.x - zm1.x) + C2f*(zp1.x - zm2.x);
                    dbz.y = C1f*(cz.y - zm1.y) + C2f*(zp1.y - zm2.y);
                    dbz.z = C1f*(cz.z - zm1.z) + C2f*(zp1.z - zm2.z);
                    dbz.w = C1f*(cz.w - zm1.w) + C2f*(zp1.w - zm2.w);
                    Pv[r].x = Ca[r].x*Pv[r].x + Cq[r].x*(dbx.x + dbz.x);
                    Pv[r].y = Ca[r].y*Pv[r].y + Cq[r].y*(dbx.y + dbz.y);
                    Pv[r].z = Ca[r].z*Pv[r].z + Cq[r].z*(dbx.z + dbz.z);
                    Pv[r].w = Ca[r].w*Pv[r].w + Cq[r].w*(dbx.w + dbz.w);
                    int gz = tz0 - Hz + zb0 + r;
                    if (gz == szv) {
                        int dcol = sxv - (tx0 - Hx + xo);
                        if      (dcol == 0) Pv[r].x += wv;
                        else if (dcol == 1) Pv[r].y += wv;
                        else if (dcol == 2) Pv[r].z += wv;
                        else if (dcol == 3) Pv[r].w += wv;
                    }
                    st4(lp + (zb0 + r) * RLX + xo, Pv[r]);
                }
            }
            __syncthreads();

            if (own) {
                float val = lp[lrcv];
                int oi = (s * NTd + t) * Rd + tid;
                if (bf) ((__hip_bfloat16*)out)[oi] = __float2bfloat16(val);
                else    ((float*)out)[oi] = val;
            }
        }

        // ---- publish tile interior to the write buffer (neighbors' halo)
        float* wp  = bW + s * NN;
        float* wvx = bW + FSZ + s * NN;
        float* wvz = bW + 2 * FSZ + s * NN;
        #pragma unroll
        for (int r = 0; r < ZB; ++r) {
            int z = zb0 + r;
            if (z >= Hz && z < Hz + TZ && xo >= Hx && xo < Hx + TX) {
                int gi = (tz0 - Hz + z) * NXd + (tx0 - Hx + xo);
                st4(wp + gi, Pv[r]);
                st4(wvx + gi, Vx[r]);
                st4(wvz + gi, Vz[r]);
            }
        }

        gbar(bar, wg);
    }
}

extern "C" void kernel_launch(void* const* d_in, const int* in_sizes, int n_in,
                              void* d_out, int out_size, void* d_ws, size_t ws_size,
                              hipStream_t stream) {
    if (ws_size < WS_NEED_BYTES) return;
    float* ws = (float*)d_ws;
    const void* vp   = d_in[0];
    const void* rho  = d_in[1];
    const void* damp = d_in[2];
    const void* wav  = d_in[3];
    const int* src_x = (const int*)d_in[4];
    const int* src_z = (const int*)d_in[5];
    const int* rcv_x = (const int*)d_in[6];
    const int* rcv_z = (const int*)d_in[7];

    // zero both state buffers + flag + barrier area (deterministic per call)
    hipMemsetAsync(ws, 0, WS_NEED_BYTES, stream);
    detect_k<<<1, 64, 0, stream>>>((const uint32_t*)vp, (int*)(ws + FLAG_OFF));
    persist_k<<<256, 512, 0, stream>>>(ws, d_out, vp, rho, damp, wav,
                                       src_x, src_z, rcv_x, rcv_z);
}

// Round 7
// 3483.896 us; speedup vs baseline: 2.0818x; 2.0818x over previous
//
#include <hip/hip_runtime.h>
#include <hip/hip_bf16.h>
#include <stdint.h>

// Persistent-kernel time-skewed acoustic FD, round 7.
// Key change vs round 6: all cross-barrier global stores are WRITE-THROUGH
// (sc0 sc1) so the grid barrier needs no L2 writeback (the round-6 fence's
// buffer_wbl2 drain was ~27 us/window). Barrier is monotonic counters +
// acquire-only fence (buffer_inv) on the wait side.

#define NXd 512
#define NZd 512
#define NTd 1000
#define Sd  2
#define Rd  512
#define C1f 1.125f
#define C2f (-1.0f/24.0f)
#define CVXf 1e-4f              // DT/DX
#define SRC_AMPf 1e-5f          // DT/(DX*DZ)

#define TZ 32
#define TX 64
#define KSTEPS 5
#define NWIN 200
#define Hz 24
#define Hx 32
#define RLZ 80
#define RLX 128
#define ZB 5

#define NN  (NZd*NXd)
#define FSZ (Sd*NN)
#define BUF_SZ (3*FSZ)
#define FLAG_OFF (2*BUF_SZ)
#define BAR_OFF  (2*BUF_SZ + 32)
#define WS_NEED_FLOATS (2*BUF_SZ + 32 + 160)
#define WS_NEED_BYTES ((size_t)WS_NEED_FLOATS * 4)

__device__ __forceinline__ float4 ld4(const float* p) { return *(const float4*)p; }
__device__ __forceinline__ void st4(float* p, float4 v) { *(float4*)p = v; }

// write-through 16B store: lands at the coherence point (L3), leaves no
// dirty L2 line -> the grid barrier needs no wbl2 drain.
__device__ __forceinline__ void st4_wt(float* p, float4 v) {
    typedef float vf4 __attribute__((ext_vector_type(4)));
    vf4 w; __builtin_memcpy(&w, &v, 16);
    asm volatile("global_store_dwordx4 %0, %1, off sc0 sc1" :: "v"(p), "v"(w) : "memory");
}
__device__ __forceinline__ void st1_wt(float* p, float v) {
    asm volatile("global_store_dword %0, %1, off sc0 sc1" :: "v"(p), "v"(v) : "memory");
}
__device__ __forceinline__ void sth_wt(void* p, unsigned short bits) {
    unsigned u = bits;
    asm volatile("global_store_short %0, %1, off sc0 sc1" :: "v"(p), "v"(u) : "memory");
}

// DPP wave shifts (verified round 5): wave_shr:1 (0x138) = value from lane-1,
// wave_shl:1 (0x130) = value from lane+1. bound_ctrl -> 0 at wave edge.
__device__ __forceinline__ float sh_up1(float v) {
    return __int_as_float(__builtin_amdgcn_update_dpp(
        0, __float_as_int(v), 0x138, 0xF, 0xF, true));
}
__device__ __forceinline__ float sh_dn1(float v) {
    return __int_as_float(__builtin_amdgcn_update_dpp(
        0, __float_as_int(v), 0x130, 0xF, 0xF, true));
}

__global__ void detect_k(const uint32_t* __restrict__ vp_raw, int* __restrict__ flag) {
    int lane = threadIdx.x;
    uint32_t u = vp_raw[lane];
    int hb = (u >> 8) & 0xFF;
    int is_exp = (hb == 0x44 || hb == 0x45) ? 1 : 0;
    unsigned long long m = __ballot(is_exp);
    if (lane == 0) *flag = (__popcll(m) >= 48) ? 1 : 0;
}

__device__ __forceinline__ float load_in(const void* p, int i, int bf) {
    return bf ? __bfloat162float(((const __hip_bfloat16*)p)[i])
              : ((const float*)p)[i];
}

// Monotonic grid barrier for window w (0-based). All publish data is already
// at the coherence point (write-through + the vmcnt(0) inside __syncthreads),
// so arrival is RELAXED. Wait side: acquire fence = buffer_inv only (clean L2).
__device__ __forceinline__ void gbar(unsigned* __restrict__ bar, int wg, int w) {
    __syncthreads();
    if (threadIdx.x == 0) {
        unsigned* gcnt = bar + (wg & 7) * 16;
        unsigned* mcnt = bar + 128;
        unsigned* gen  = bar + 144;
        unsigned tgt = (unsigned)(w + 1);
        unsigned a = __hip_atomic_fetch_add(gcnt, 1u, __ATOMIC_RELAXED, __HIP_MEMORY_SCOPE_AGENT);
        if (a == 32u * tgt - 1u) {
            unsigned m = __hip_atomic_fetch_add(mcnt, 1u, __ATOMIC_RELAXED, __HIP_MEMORY_SCOPE_AGENT);
            if (m == 8u * tgt - 1u) {
                __hip_atomic_store(gen, tgt, __ATOMIC_RELEASE, __HIP_MEMORY_SCOPE_AGENT);
            }
        }
        for (int it = 0; it < 300000; ++it) {   // capped spin: no infinite hang
            if (__hip_atomic_load(gen, __ATOMIC_RELAXED, __HIP_MEMORY_SCOPE_AGENT) >= tgt) break;
            __builtin_amdgcn_s_sleep(2);
        }
        __builtin_amdgcn_fence(__ATOMIC_ACQUIRE, "agent");   // buffer_inv, no wbl2
    }
    __syncthreads();
}

__global__ __launch_bounds__(512, 2) void persist_k(float* __restrict__ ws,
        void* __restrict__ out, const void* __restrict__ vp,
        const void* __restrict__ rho, const void* __restrict__ damp,
        const void* __restrict__ wav,
        const int* __restrict__ sxp, const int* __restrict__ szp,
        const int* __restrict__ rxp, const int* __restrict__ rzp) {
    __shared__ float lp [RLZ*RLX];
    __shared__ float lvz[RLZ*RLX + 1200];   // pad: LDS 86.7KB -> 1 WG/CU forced

    const int tid  = threadIdx.x;
    const int xg   = tid & 31;
    const int zblk = tid >> 5;
    const int zb0  = zblk * ZB;
    const int xo   = xg * 4;

    const int wg  = blockIdx.x;
    const int xcd = wg & 7;
    const int ii  = wg >> 3;
    const int s   = ii >> 4;
    const int loc = ii & 15;
    const int tz0 = ((xcd >> 1) * 4 + (loc >> 2)) * TZ;
    const int tx0 = ((xcd & 1) * 4 + (loc & 3)) * TX;
    const int bf  = *(const int*)(ws + FLAG_OFF);
    unsigned* bar = (unsigned*)(ws + BAR_OFF);

    const int rxv = rxp[tid], rzv = rzp[tid];
    const bool own = (rzv >= tz0 && rzv < tz0 + TZ && rxv >= tx0 && rxv < tx0 + TX);
    const int lrcv = (rzv - tz0 + Hz) * RLX + (rxv - tx0 + Hx);
    const int sxv = sxp[s], szv = szp[s];

    const int zPm  = (zb0 - 1 < 0) ? 0 : zb0 - 1;
    const int zPn0 = (zb0 + ZB     > RLZ - 1) ? RLZ - 1 : zb0 + ZB;
    const int zPn1 = (zb0 + ZB + 1 > RLZ - 1) ? RLZ - 1 : zb0 + ZB + 1;
    const int zVm2 = (zb0 - 2 < 0) ? 0 : zb0 - 2;
    const int zVm1 = zPm;
    const int zVn0 = zPn0;

    const float4 zero4 = {0.f, 0.f, 0.f, 0.f};

    // ---- coefficients: loaded ONCE, live in registers for the whole run
    float4 Ca[ZB], Cb[ZB], Cq[ZB];
    #pragma unroll
    for (int r = 0; r < ZB; ++r) {
        int gz = tz0 - Hz + zb0 + r;
        int gx = tx0 - Hx + xo;
        float4 a = zero4, b = zero4, q = zero4;
        if (gz >= 0 && gz < NZd) {
            #pragma unroll
            for (int c = 0; c < 4; ++c) {
                int x = gx + c;
                if (x >= 0 && x < NXd) {
                    int gi = gz * NXd + x;
                    float v  = load_in(vp,  gi, bf);
                    float rr = load_in(rho, gi, bf);
                    float d  = load_in(damp, gi, bf);
                    ((float*)&a)[c] = d;
                    ((float*)&b)[c] = d * (CVXf / rr);
                    ((float*)&q)[c] = d * (CVXf * rr * v * v);
                }
            }
        }
        Ca[r] = a; Cb[r] = b; Cq[r] = q;
    }

    float4 Pv[ZB], Vx[ZB], Vz[ZB];
    #pragma unroll
    for (int r = 0; r < ZB; ++r) { Pv[r] = zero4; Vx[r] = zero4; Vz[r] = zero4; }

    for (int w = 0; w < NWIN; ++w) {
        const float* bR = ws + (w & 1) * BUF_SZ;
        float*       bW = ws + ((w + 1) & 1) * BUF_SZ;
        const float* rp  = bR + s * NN;
        const float* rvx = bR + FSZ + s * NN;
        const float* rvz = bR + 2 * FSZ + s * NN;

        // ---- halo refresh (tile interior stays in registers) + LDS fill
        #pragma unroll
        for (int r = 0; r < ZB; ++r) {
            int z = zb0 + r;
            int gz = tz0 - Hz + z;
            int gx = tx0 - Hx + xo;
            int li = z * RLX + xo;
            bool intile = (z >= Hz && z < Hz + TZ && xo >= Hx && xo < Hx + TX);
            if (!intile) {
                bool in = (gz >= 0) && (gz < NZd) && (gx >= 0) && (gx < NXd);
                if (in) {
                    int gi = gz * NXd + gx;
                    Pv[r] = ld4(rp + gi); Vx[r] = ld4(rvx + gi); Vz[r] = ld4(rvz + gi);
                } else {
                    Pv[r] = zero4; Vx[r] = zero4; Vz[r] = zero4;
                }
            }
            st4(lp + li, Pv[r]);
            st4(lvz + li, Vz[r]);
        }
        __syncthreads();

        for (int j = 0; j < KSTEPS; ++j) {
            const int t = w * KSTEPS + j;
            const float wv = (bf ? __bfloat162float(((const __hip_bfloat16*)wav)[s*NTd + t])
                                 : ((const float*)wav)[s*NTd + t]) * SRC_AMPf;

            const int mV = 4 * (KSTEPS - 1 - j) + 2;
            const int mP = mV - 2;
            const bool actV = (zb0 + ZB > Hz - mV) && (zb0 < Hz + TZ + mV);
            const bool actP = (zb0 + ZB > Hz - mP) && (zb0 < Hz + TZ + mP);

            // ---------- V phase
            if (actV) {
                float4 pPm  = ld4(lp + zPm  * RLX + xo);
                float4 pNx0 = ld4(lp + zPn0 * RLX + xo);
                float4 pNx1 = ld4(lp + zPn1 * RLX + xo);
                #pragma unroll
                for (int r = 0; r < ZB; ++r) {
                    float4 c = Pv[r];
                    float pmw = sh_up1(c.w);
                    float ppx = sh_dn1(c.x);
                    float ppy = sh_dn1(c.y);
                    float4 pzm = (r == 0) ? pPm : Pv[(r == 0) ? 0 : r - 1];
                    float4 pz1 = (r == ZB-1) ? pNx0 : Pv[(r == ZB-1) ? ZB-1 : r + 1];
                    float4 pz2 = (r == ZB-1) ? pNx1 : ((r == ZB-2) ? pNx0 : Pv[(r >= ZB-2) ? ZB-1 : r + 2]);
                    float4 dfx, dfz;
                    dfx.x = C1f*(c.y - c.x) + C2f*(c.z - pmw);
                    dfx.y = C1f*(c.z - c.y) + C2f*(c.w - c.x);
                    dfx.z = C1f*(c.w - c.z) + C2f*(ppx - c.y);
                    dfx.w = C1f*(ppx - c.w) + C2f*(ppy - c.z);
                    dfz.x = C1f*(pz1.x - c.x) + C2f*(pz2.x - pzm.x);
                    dfz.y = C1f*(pz1.y - c.y) + C2f*(pz2.y - pzm.y);
                    dfz.z = C1f*(pz1.z - c.z) + C2f*(pz2.z - pzm.z);
                    dfz.w = C1f*(pz1.w - c.w) + C2f*(pz2.w - pzm.w);
                    Vx[r].x = Ca[r].x*Vx[r].x + Cb[r].x*dfx.x;
                    Vx[r].y = Ca[r].y*Vx[r].y + Cb[r].y*dfx.y;
                    Vx[r].z = Ca[r].z*Vx[r].z + Cb[r].z*dfx.z;
                    Vx[r].w = Ca[r].w*Vx[r].w + Cb[r].w*dfx.w;
                    Vz[r].x = Ca[r].x*Vz[r].x + Cb[r].x*dfz.x;
                    Vz[r].y = Ca[r].y*Vz[r].y + Cb[r].y*dfz.y;
                    Vz[r].z = Ca[r].z*Vz[r].z + Cb[r].z*dfz.z;
                    Vz[r].w = Ca[r].w*Vz[r].w + Cb[r].w*dfz.w;
                }
                st4(lvz + (zb0 + 0) * RLX + xo, Vz[0]);
                st4(lvz + (zb0 + 3) * RLX + xo, Vz[3]);
                st4(lvz + (zb0 + 4) * RLX + xo, Vz[4]);
            }
            __syncthreads();

            // ---------- P phase
            if (actP) {
                float4 vm2 = ld4(lvz + zVm2 * RLX + xo);
                float4 vm1 = ld4(lvz + zVm1 * RLX + xo);
                float4 vn0 = ld4(lvz + zVn0 * RLX + xo);
                #pragma unroll
                for (int r = 0; r < ZB; ++r) {
                    float4 cx = Vx[r], cz = Vz[r];
                    float vmz = sh_up1(cx.z);
                    float vmw = sh_up1(cx.w);
                    float vpx = sh_dn1(cx.x);
                    float4 zm2 = (r == 0) ? vm2 : ((r == 1) ? vm1 : Vz[(r >= 2) ? r - 2 : 0]);
                    float4 zm1 = (r == 0) ? vm1 : Vz[(r == 0) ? 0 : r - 1];
                    float4 zp1 = (r == ZB-1) ? vn0 : Vz[(r == ZB-1) ? ZB-1 : r + 1];
                    float4 dbx, dbz;
                    dbx.x = C1f*(cx.x - vmw)  + C2f*(cx.y - vmz);
                    dbx.y = C1f*(cx.y - cx.x) + C2f*(cx.z - vmw);
                    dbx.z = C1f*(cx.z - cx.y) + C2f*(cx.w - cx.x);
                    dbx.w = C1f*(cx.w - cx.z) + C2f*(vpx  - cx.y);
                    dbz.x = C1f*(cz.x - zm1.x) + C2f*(zp1.x - zm2.x);
                    dbz.y = C1f*(cz.y - zm1.y) + C2f*(zp1.y - zm2.y);
                    dbz.z = C1f*(cz.z - zm1.z) + C2f*(zp1.z - zm2.z);
                    dbz.w = C1f*(cz.w - zm1.w) + C2f*(zp1.w - zm2.w);
                    Pv[r].x = Ca[r].x*Pv[r].x + Cq[r].x*(dbx.x + dbz.x);
                    Pv[r].y = Ca[r].y*Pv[r].y + Cq[r].y*(dbx.y + dbz.y);
                    Pv[r].z = Ca[r].z*Pv[r].z + Cq[r].z*(dbx.z + dbz.z);
                    Pv[r].w = Ca[r].w*Pv[r].w + Cq[r].w*(dbx.w + dbz.w);
                    int gz = tz0 - Hz + zb0 + r;
                    if (gz == szv) {
                        int dcol = sxv - (tx0 - Hx + xo);
                        if      (dcol == 0) Pv[r].x += wv;
                        else if (dcol == 1) Pv[r].y += wv;
                        else if (dcol == 2) Pv[r].z += wv;
                        else if (dcol == 3) Pv[r].w += wv;
                    }
                    st4(lp + (zb0 + r) * RLX + xo, Pv[r]);
                }
            }
            __syncthreads();

            if (own) {
                float val = lp[lrcv];
                int oi = (s * NTd + t) * Rd + tid;
                if (bf) {
                    __hip_bfloat16 h = __float2bfloat16(val);
                    unsigned short bits; __builtin_memcpy(&bits, &h, 2);
                    sth_wt((__hip_bfloat16*)out + oi, bits);
                } else {
                    st1_wt((float*)out + oi, val);
                }
            }
        }

        // ---- publish tile interior (write-through: no dirty L2 at barrier)
        float* wp  = bW + s * NN;
        float* wvx = bW + FSZ + s * NN;
        float* wvz = bW + 2 * FSZ + s * NN;
        #pragma unroll
        for (int r = 0; r < ZB; ++r) {
            int z = zb0 + r;
            if (z >= Hz && z < Hz + TZ && xo >= Hx && xo < Hx + TX) {
                int gi = (tz0 - Hz + z) * NXd + (tx0 - Hx + xo);
                st4_wt(wp + gi, Pv[r]);
                st4_wt(wvx + gi, Vx[r]);
                st4_wt(wvz + gi, Vz[r]);
            }
        }

        if (w < NWIN - 1) gbar(bar, wg, w);
    }
}

extern "C" void kernel_launch(void* const* d_in, const int* in_sizes, int n_in,
                              void* d_out, int out_size, void* d_ws, size_t ws_size,
                              hipStream_t stream) {
    if (ws_size < WS_NEED_BYTES) return;
    float* ws = (float*)d_ws;
    const void* vp   = d_in[0];
    const void* rho  = d_in[1];
    const void* damp = d_in[2];
    const void* wav  = d_in[3];
    const int* src_x = (const int*)d_in[4];
    const int* src_z = (const int*)d_in[5];
    const int* rcv_x = (const int*)d_in[6];
    const int* rcv_z = (const int*)d_in[7];

    hipMemsetAsync(ws, 0, WS_NEED_BYTES, stream);
    detect_k<<<1, 64, 0, stream>>>((const uint32_t*)vp, (int*)(ws + FLAG_OFF));
    persist_k<<<256, 512, 0, stream>>>(ws, d_out, vp, rho, damp, wav,
                                       src_x, src_z, rcv_x, rcv_z);
}

// Round 8
// 3280.216 us; speedup vs baseline: 2.2110x; 1.0621x over previous
//
#include <hip/hip_runtime.h>
#include <hip/hip_bf16.h>
#include <stdint.h>

// Persistent time-skewed acoustic FD, round 8.
// K=7 steps/window (143 windows), 768 threads (3 waves/SIMD), ZB=4 rows
// per thread, compact cross-block vz buffer. Write-through publish +
// monotonic barrier with acquire-only fence (round-7 verified).

#define NXd 512
#define NZd 512
#define NTd 1000
#define Sd  2
#define Rd  512
#define C1f 1.125f
#define C2f (-1.0f/24.0f)
#define CVXf 1e-4f              // DT/DX
#define SRC_AMPf 1e-5f          // DT/(DX*DZ)

#define TZ 32
#define TX 64
#define KSTEPS 7
#define NWIN 143                // 142*7 + 6 = 1000
#define Hz 32
#define Hx 32
#define RLZ 96                  // TZ + 2*Hz
#define RLX 128                 // TX + 2*Hx
#define ZB 4                    // rows per thread
#define NZBLK 24                // RLZ/ZB
#define NTHR 768                // NZBLK*32

#define NN  (NZd*NXd)
#define FSZ (Sd*NN)
#define BUF_SZ (3*FSZ)
#define FLAG_OFF (2*BUF_SZ)
#define BAR_OFF  (2*BUF_SZ + 32)
#define WS_NEED_FLOATS (2*BUF_SZ + 32 + 160)
#define WS_NEED_BYTES ((size_t)WS_NEED_FLOATS * 4)

__device__ __forceinline__ float4 ld4(const float* p) { return *(const float4*)p; }
__device__ __forceinline__ void st4(float* p, float4 v) { *(float4*)p = v; }

// write-through 16B store: lands at the coherence point, no dirty L2 line.
__device__ __forceinline__ void st4_wt(float* p, float4 v) {
    typedef float vf4 __attribute__((ext_vector_type(4)));
    vf4 w; __builtin_memcpy(&w, &v, 16);
    asm volatile("global_store_dwordx4 %0, %1, off sc0 sc1" :: "v"(p), "v"(w) : "memory");
}
__device__ __forceinline__ void st1_wt(float* p, float v) {
    asm volatile("global_store_dword %0, %1, off sc0 sc1" :: "v"(p), "v"(v) : "memory");
}
__device__ __forceinline__ void sth_wt(void* p, unsigned short bits) {
    unsigned u = bits;
    asm volatile("global_store_short %0, %1, off sc0 sc1" :: "v"(p), "v"(u) : "memory");
}

// DPP wave shifts (verified round 5): wave_shr:1 (0x138) = value from lane-1,
// wave_shl:1 (0x130) = value from lane+1. bound_ctrl -> 0 at wave edge.
__device__ __forceinline__ float sh_up1(float v) {
    return __int_as_float(__builtin_amdgcn_update_dpp(
        0, __float_as_int(v), 0x138, 0xF, 0xF, true));
}
__device__ __forceinline__ float sh_dn1(float v) {
    return __int_as_float(__builtin_amdgcn_update_dpp(
        0, __float_as_int(v), 0x130, 0xF, 0xF, true));
}

__global__ void detect_k(const uint32_t* __restrict__ vp_raw, int* __restrict__ flag) {
    int lane = threadIdx.x;
    uint32_t u = vp_raw[lane];
    int hb = (u >> 8) & 0xFF;
    int is_exp = (hb == 0x44 || hb == 0x45) ? 1 : 0;
    unsigned long long m = __ballot(is_exp);
    if (lane == 0) *flag = (__popcll(m) >= 48) ? 1 : 0;
}

__device__ __forceinline__ float load_in(const void* p, int i, int bf) {
    return bf ? __bfloat162float(((const __hip_bfloat16*)p)[i])
              : ((const float*)p)[i];
}

// Monotonic grid barrier (round-7 verified): relaxed tree arrival (data is
// already at coherence point), acquire fence (buffer_inv only) on wake.
__device__ __forceinline__ void gbar(unsigned* __restrict__ bar, int wg, int w) {
    __syncthreads();
    if (threadIdx.x == 0) {
        unsigned* gcnt = bar + (wg & 7) * 16;
        unsigned* mcnt = bar + 128;
        unsigned* gen  = bar + 144;
        unsigned tgt = (unsigned)(w + 1);
        unsigned a = __hip_atomic_fetch_add(gcnt, 1u, __ATOMIC_RELAXED, __HIP_MEMORY_SCOPE_AGENT);
        if (a == 32u * tgt - 1u) {
            unsigned m = __hip_atomic_fetch_add(mcnt, 1u, __ATOMIC_RELAXED, __HIP_MEMORY_SCOPE_AGENT);
            if (m == 8u * tgt - 1u) {
                __hip_atomic_store(gen, tgt, __ATOMIC_RELEASE, __HIP_MEMORY_SCOPE_AGENT);
            }
        }
        for (int it = 0; it < 300000; ++it) {
            if (__hip_atomic_load(gen, __ATOMIC_RELAXED, __HIP_MEMORY_SCOPE_AGENT) >= tgt) break;
            __builtin_amdgcn_s_sleep(2);
        }
        __builtin_amdgcn_fence(__ATOMIC_ACQUIRE, "agent");
    }
    __syncthreads();
}

__global__ __launch_bounds__(NTHR, 3) void persist_k(float* __restrict__ ws,
        void* __restrict__ out, const void* __restrict__ vp,
        const void* __restrict__ rho, const void* __restrict__ damp,
        const void* __restrict__ wav,
        const int* __restrict__ sxp, const int* __restrict__ szp,
        const int* __restrict__ rxp, const int* __restrict__ rzp) {
    __shared__ float lp  [RLZ*RLX];          // 48 KB: all p rows
    __shared__ float lvzc[NZBLK*3*RLX];      // 36 KB: vz rows {0,2,3}/block
    // total 84 KB -> 1 WG/CU (2x84 > 160), co-residency for the barrier

    const int tid  = threadIdx.x;
    const int xg   = tid & 31;
    const int zblk = tid >> 5;               // 0..23
    const int zb0  = zblk * ZB;
    const int xo   = xg * 4;

    const int wg  = blockIdx.x;
    const int xcd = wg & 7;
    const int ii  = wg >> 3;
    const int s   = ii >> 4;
    const int loc = ii & 15;
    const int tz0 = ((xcd >> 1) * 4 + (loc >> 2)) * TZ;
    const int tx0 = ((xcd & 1) * 4 + (loc & 3)) * TX;
    const int bf  = *(const int*)(ws + FLAG_OFF);
    unsigned* bar = (unsigned*)(ws + BAR_OFF);

    const int rxv = (tid < Rd) ? rxp[tid] : 0;
    const int rzv = (tid < Rd) ? rzp[tid] : -1000;
    const bool own = (tid < Rd) && (rzv >= tz0 && rzv < tz0 + TZ &&
                                    rxv >= tx0 && rxv < tx0 + TX);
    const int lrcv = (rzv - tz0 + Hz) * RLX + (rxv - tx0 + Hx);
    const int sxv = sxp[s], szv = szp[s];

    // clamped cross-block row indices (region edges tolerate garbage)
    const int zPm  = (zb0 - 1 < 0) ? 0 : zb0 - 1;            // lp: prev row 3
    const int zPn0 = (zb0 + ZB     > RLZ - 1) ? RLZ - 1 : zb0 + ZB;
    const int zPn1 = (zb0 + ZB + 1 > RLZ - 1) ? RLZ - 1 : zb0 + ZB + 1;
    // lvzc compact rows: block b publishes {r0->b*3+0, r2->b*3+1, r3->b*3+2}
    const int cVm2 = (zblk > 0) ? (zblk - 1) * 3 + 1 : 0;            // zb0-2
    const int cVm1 = (zblk > 0) ? (zblk - 1) * 3 + 2 : 0;            // zb0-1
    const int cVn0 = (zblk < NZBLK - 1) ? (zblk + 1) * 3 + 0
                                        : (NZBLK - 1) * 3 + 2;       // zb0+4

    const float4 zero4 = {0.f, 0.f, 0.f, 0.f};

    // ---- coefficients: loaded once, register-resident for the whole run
    float4 Ca[ZB], Cb[ZB], Cq[ZB];
    #pragma unroll
    for (int r = 0; r < ZB; ++r) {
        int gz = tz0 - Hz + zb0 + r;
        int gx = tx0 - Hx + xo;
        float4 a = zero4, b = zero4, q = zero4;
        if (gz >= 0 && gz < NZd) {
            #pragma unroll
            for (int c = 0; c < 4; ++c) {
                int x = gx + c;
                if (x >= 0 && x < NXd) {
                    int gi = gz * NXd + x;
                    float v  = load_in(vp,  gi, bf);
                    float rr = load_in(rho, gi, bf);
                    float d  = load_in(damp, gi, bf);
                    ((float*)&a)[c] = d;
                    ((float*)&b)[c] = d * (CVXf / rr);
                    ((float*)&q)[c] = d * (CVXf * rr * v * v);
                }
            }
        }
        Ca[r] = a; Cb[r] = b; Cq[r] = q;
    }

    float4 Pv[ZB], Vx[ZB], Vz[ZB];
    #pragma unroll
    for (int r = 0; r < ZB; ++r) { Pv[r] = zero4; Vx[r] = zero4; Vz[r] = zero4; }

    for (int w = 0; w < NWIN; ++w) {
        const int kk = (NTd - w * KSTEPS < KSTEPS) ? (NTd - w * KSTEPS) : KSTEPS;
        const float* bR = ws + (w & 1) * BUF_SZ;
        float*       bW = ws + ((w + 1) & 1) * BUF_SZ;
        const float* rp  = bR + s * NN;
        const float* rvx = bR + FSZ + s * NN;
        const float* rvz = bR + 2 * FSZ + s * NN;

        // ---- halo refresh (tile interior stays in registers) + lp fill
        #pragma unroll
        for (int r = 0; r < ZB; ++r) {
            int z = zb0 + r;
            int gz = tz0 - Hz + z;
            int gx = tx0 - Hx + xo;
            bool intile = (z >= Hz && z < Hz + TZ && xo >= Hx && xo < Hx + TX);
            if (!intile) {
                bool in = (gz >= 0) && (gz < NZd) && (gx >= 0) && (gx < NXd);
                if (in) {
                    int gi = gz * NXd + gx;
                    Pv[r] = ld4(rp + gi); Vx[r] = ld4(rvx + gi); Vz[r] = ld4(rvz + gi);
                } else {
                    Pv[r] = zero4; Vx[r] = zero4; Vz[r] = zero4;
                }
            }
            st4(lp + z * RLX + xo, Pv[r]);
        }
        __syncthreads();

        for (int j = 0; j < kk; ++j) {
            const int t = w * KSTEPS + j;
            const float wv = (bf ? __bfloat162float(((const __hip_bfloat16*)wav)[s*NTd + t])
                                 : ((const float*)wav)[s*NTd + t]) * SRC_AMPf;

            const int mV = 4 * (kk - 1 - j) + 2;
            const int mP = mV - 2;
            const bool actV = (zb0 + ZB > Hz - mV) && (zb0 < Hz + TZ + mV);
            const bool actP = (zb0 + ZB > Hz - mP) && (zb0 < Hz + TZ + mP);

            // ---------- V phase: vx,vz <- A*v + B*df(p)
            if (actV) {
                float4 pPm  = ld4(lp + zPm  * RLX + xo);
                float4 pNx0 = ld4(lp + zPn0 * RLX + xo);
                float4 pNx1 = ld4(lp + zPn1 * RLX + xo);
                #pragma unroll
                for (int r = 0; r < ZB; ++r) {
                    float4 c = Pv[r];
                    float pmw = sh_up1(c.w);
                    float ppx = sh_dn1(c.x);
                    float ppy = sh_dn1(c.y);
                    float4 pzm = (r == 0) ? pPm : Pv[(r == 0) ? 0 : r - 1];
                    float4 pz1 = (r == ZB-1) ? pNx0 : Pv[(r == ZB-1) ? ZB-1 : r + 1];
                    float4 pz2 = (r == ZB-2) ? pNx0 : ((r == ZB-1) ? pNx1 : Pv[(r >= ZB-2) ? ZB-1 : r + 2]);
                    float4 dfx, dfz;
                    dfx.x = C1f*(c.y - c.x) + C2f*(c.z - pmw);
                    dfx.y = C1f*(c.z - c.y) + C2f*(c.w - c.x);
                    dfx.z = C1f*(c.w - c.z) + C2f*(ppx - c.y);
                    dfx.w = C1f*(ppx - c.w) + C2f*(ppy - c.z);
                    dfz.x = C1f*(pz1.x - c.x) + C2f*(pz2.x - pzm.x);
                    dfz.y = C1f*(pz1.y - c.y) + C2f*(pz2.y - pzm.y);
                    dfz.z = C1f*(pz1.z - c.z) + C2f*(pz2.z - pzm.z);
                    dfz.w = C1f*(pz1.w - c.w) + C2f*(pz2.w - pzm.w);
                    Vx[r].x = Ca[r].x*Vx[r].x + Cb[r].x*dfx.x;
                    Vx[r].y = Ca[r].y*Vx[r].y + Cb[r].y*dfx.y;
                    Vx[r].z = Ca[r].z*Vx[r].z + Cb[r].z*dfx.z;
                    Vx[r].w = Ca[r].w*Vx[r].w + Cb[r].w*dfx.w;
                    Vz[r].x = Ca[r].x*Vz[r].x + Cb[r].x*dfz.x;
                    Vz[r].y = Ca[r].y*Vz[r].y + Cb[r].y*dfz.y;
                    Vz[r].z = Ca[r].z*Vz[r].z + Cb[r].z*dfz.z;
                    Vz[r].w = Ca[r].w*Vz[r].w + Cb[r].w*dfz.w;
                }
                // publish cross-block vz rows {0,2,3} -> compact slots
                st4(lvzc + (zblk*3 + 0) * RLX + xo, Vz[0]);
                st4(lvzc + (zblk*3 + 1) * RLX + xo, Vz[2]);
                st4(lvzc + (zblk*3 + 2) * RLX + xo, Vz[3]);
            }
            __syncthreads();

            // ---------- P phase: p <- A*p + Q*(dbx(vx)+dbz(vz)) [+ source]
            if (actP) {
                float4 vm2 = ld4(lvzc + cVm2 * RLX + xo);
                float4 vm1 = ld4(lvzc + cVm1 * RLX + xo);
                float4 vn0 = ld4(lvzc + cVn0 * RLX + xo);
                #pragma unroll
                for (int r = 0; r < ZB; ++r) {
                    float4 cx = Vx[r], cz = Vz[r];
                    float vmz = sh_up1(cx.z);
                    float vmw = sh_up1(cx.w);
                    float vpx = sh_dn1(cx.x);
                    float4 zm2 = (r == 0) ? vm2 : ((r == 1) ? vm1 : Vz[(r >= 2) ? r - 2 : 0]);
                    float4 zm1 = (r == 0) ? vm1 : Vz[(r == 0) ? 0 : r - 1];
                    float4 zp1 = (r == ZB-1) ? vn0 : Vz[(r == ZB-1) ? ZB-1 : r + 1];
                    float4 dbx, dbz;
                    dbx.x = C1f*(cx.x - vmw)  + C2f*(cx.y - vmz);
                    dbx.y = C1f*(cx.y - cx.x) + C2f*(cx.z - vmw);
                    dbx.z = C1f*(cx.z - cx.y) + C2f*(cx.w - cx.x);
                    dbx.w = C1f*(cx.w - cx.z) + C2f*(vpx  - cx.y);
                    dbz.x = C1f*(cz.x - zm1.x) + C2f*(zp1.x - zm2.x);
                    dbz.y = C1f*(cz.y - zm1.y) + C2f*(zp1.y - zm2.y);
                    dbz.z = C1f*(cz.z - zm1.z) + C2f*(zp1.z - zm2.z);
                    dbz.w = C1f*(cz.w - zm1.w) + C2f*(zp1.w - zm2.w);
                    Pv[r].x = Ca[r].x*Pv[r].x + Cq[r].x*(dbx.x + dbz.x);
                    Pv[r].y = Ca[r].y*Pv[r].y + Cq[r].y*(dbx.y + dbz.y);
                    Pv[r].z = Ca[r].z*Pv[r].z + Cq[r].z*(dbx.z + dbz.z);
                    Pv[r].w = Ca[r].w*Pv[r].w + Cq[r].w*(dbx.w + dbz.w);
                    int gz = tz0 - Hz + zb0 + r;
                    if (gz == szv) {
                        int dcol = sxv - (tx0 - Hx + xo);
                        if      (dcol == 0) Pv[r].x += wv;
                        else if (dcol == 1) Pv[r].y += wv;
                        else if (dcol == 2) Pv[r].z += wv;
                        else if (dcol == 3) Pv[r].w += wv;
                    }
                    st4(lp + (zb0 + r) * RLX + xo, Pv[r]);
                }
            }
            __syncthreads();

            if (own) {
                float val = lp[lrcv];
                int oi = (s * NTd + t) * Rd + tid;
                if (bf) {
                    __hip_bfloat16 h = __float2bfloat16(val);
                    unsigned short bits; __builtin_memcpy(&bits, &h, 2);
                    sth_wt((__hip_bfloat16*)out + oi, bits);
                } else {
                    st1_wt((float*)out + oi, val);
                }
            }
        }

        // ---- publish tile interior (write-through: no dirty L2 at barrier)
        float* wp  = bW + s * NN;
        float* wvx = bW + FSZ + s * NN;
        float* wvz = bW + 2 * FSZ + s * NN;
        #pragma unroll
        for (int r = 0; r < ZB; ++r) {
            int z = zb0 + r;
            if (z >= Hz && z < Hz + TZ && xo >= Hx && xo < Hx + TX) {
                int gi = (tz0 - Hz + z) * NXd + (tx0 - Hx + xo);
                st4_wt(wp + gi, Pv[r]);
                st4_wt(wvx + gi, Vx[r]);
                st4_wt(wvz + gi, Vz[r]);
            }
        }

        if (w < NWIN - 1) gbar(bar, wg, w);
    }
}

extern "C" void kernel_launch(void* const* d_in, const int* in_sizes, int n_in,
                              void* d_out, int out_size, void* d_ws, size_t ws_size,
                              hipStream_t stream) {
    if (ws_size < WS_NEED_BYTES) return;
    float* ws = (float*)d_ws;
    const void* vp   = d_in[0];
    const void* rho  = d_in[1];
    const void* damp = d_in[2];
    const void* wav  = d_in[3];
    const int* src_x = (const int*)d_in[4];
    const int* src_z = (const int*)d_in[5];
    const int* rcv_x = (const int*)d_in[6];
    const int* rcv_z = (const int*)d_in[7];

    hipMemsetAsync(ws, 0, WS_NEED_BYTES, stream);
    detect_k<<<1, 64, 0, stream>>>((const uint32_t*)vp, (int*)(ws + FLAG_OFF));
    persist_k<<<256, NTHR, 0, stream>>>(ws, d_out, vp, rho, damp, wav,
                                        src_x, src_z, rcv_x, rcv_z);
}

// Round 9
// 3132.267 us; speedup vs baseline: 2.3155x; 1.0472x over previous
//
#include <hip/hip_runtime.h>
#include <hip/hip_bf16.h>
#include <stdint.h>

// Persistent time-skewed acoustic FD, round 9.
// K=7 steps/window (143 windows), 1024 threads (4 waves/SIMD), ZB=3 rows
// per thread. Write-through publish + monotonic barrier with acquire-only
// fence (round-7/8 verified). Stencil/trapezoid numerics identical.

#define NXd 512
#define NZd 512
#define NTd 1000
#define Sd  2
#define Rd  512
#define C1f 1.125f
#define C2f (-1.0f/24.0f)
#define CVXf 1e-4f              // DT/DX
#define SRC_AMPf 1e-5f          // DT/(DX*DZ)

#define TZ 32
#define TX 64
#define KSTEPS 7
#define NWIN 143                // 142*7 + 6 = 1000
#define Hz 32
#define Hx 32
#define RLZ 96                  // TZ + 2*Hz
#define RLX 128                 // TX + 2*Hx
#define ZB 3                    // rows per thread
#define NZBLK 32                // RLZ/ZB
#define NTHR 1024               // NZBLK*32

#define NN  (NZd*NXd)
#define FSZ (Sd*NN)
#define BUF_SZ (3*FSZ)
#define FLAG_OFF (2*BUF_SZ)
#define BAR_OFF  (2*BUF_SZ + 32)
#define WS_NEED_FLOATS (2*BUF_SZ + 32 + 160)
#define WS_NEED_BYTES ((size_t)WS_NEED_FLOATS * 4)

__device__ __forceinline__ float4 ld4(const float* p) { return *(const float4*)p; }
__device__ __forceinline__ void st4(float* p, float4 v) { *(float4*)p = v; }

// write-through 16B store: lands at the coherence point, no dirty L2 line.
__device__ __forceinline__ void st4_wt(float* p, float4 v) {
    typedef float vf4 __attribute__((ext_vector_type(4)));
    vf4 w; __builtin_memcpy(&w, &v, 16);
    asm volatile("global_store_dwordx4 %0, %1, off sc0 sc1" :: "v"(p), "v"(w) : "memory");
}
__device__ __forceinline__ void st1_wt(float* p, float v) {
    asm volatile("global_store_dword %0, %1, off sc0 sc1" :: "v"(p), "v"(v) : "memory");
}
__device__ __forceinline__ void sth_wt(void* p, unsigned short bits) {
    unsigned u = bits;
    asm volatile("global_store_short %0, %1, off sc0 sc1" :: "v"(p), "v"(u) : "memory");
}

// DPP wave shifts (verified round 5): wave_shr:1 (0x138) = value from lane-1,
// wave_shl:1 (0x130) = value from lane+1. bound_ctrl -> 0 at wave edge.
__device__ __forceinline__ float sh_up1(float v) {
    return __int_as_float(__builtin_amdgcn_update_dpp(
        0, __float_as_int(v), 0x138, 0xF, 0xF, true));
}
__device__ __forceinline__ float sh_dn1(float v) {
    return __int_as_float(__builtin_amdgcn_update_dpp(
        0, __float_as_int(v), 0x130, 0xF, 0xF, true));
}

__global__ void detect_k(const uint32_t* __restrict__ vp_raw, int* __restrict__ flag) {
    int lane = threadIdx.x;
    uint32_t u = vp_raw[lane];
    int hb = (u >> 8) & 0xFF;
    int is_exp = (hb == 0x44 || hb == 0x45) ? 1 : 0;
    unsigned long long m = __ballot(is_exp);
    if (lane == 0) *flag = (__popcll(m) >= 48) ? 1 : 0;
}

__device__ __forceinline__ float load_in(const void* p, int i, int bf) {
    return bf ? __bfloat162float(((const __hip_bfloat16*)p)[i])
              : ((const float*)p)[i];
}

// Monotonic grid barrier (round-7 verified): relaxed tree arrival (data is
// already at coherence point), acquire fence (buffer_inv only) on wake.
__device__ __forceinline__ void gbar(unsigned* __restrict__ bar, int wg, int w) {
    __syncthreads();
    if (threadIdx.x == 0) {
        unsigned* gcnt = bar + (wg & 7) * 16;
        unsigned* mcnt = bar + 128;
        unsigned* gen  = bar + 144;
        unsigned tgt = (unsigned)(w + 1);
        unsigned a = __hip_atomic_fetch_add(gcnt, 1u, __ATOMIC_RELAXED, __HIP_MEMORY_SCOPE_AGENT);
        if (a == 32u * tgt - 1u) {
            unsigned m = __hip_atomic_fetch_add(mcnt, 1u, __ATOMIC_RELAXED, __HIP_MEMORY_SCOPE_AGENT);
            if (m == 8u * tgt - 1u) {
                __hip_atomic_store(gen, tgt, __ATOMIC_RELEASE, __HIP_MEMORY_SCOPE_AGENT);
            }
        }
        for (int it = 0; it < 300000; ++it) {
            if (__hip_atomic_load(gen, __ATOMIC_RELAXED, __HIP_MEMORY_SCOPE_AGENT) >= tgt) break;
            __builtin_amdgcn_s_sleep(2);
        }
        __builtin_amdgcn_fence(__ATOMIC_ACQUIRE, "agent");
    }
    __syncthreads();
}

__global__ __launch_bounds__(NTHR) void persist_k(float* __restrict__ ws,
        void* __restrict__ out, const void* __restrict__ vp,
        const void* __restrict__ rho, const void* __restrict__ damp,
        const void* __restrict__ wav,
        const int* __restrict__ sxp, const int* __restrict__ szp,
        const int* __restrict__ rxp, const int* __restrict__ rzp) {
    __shared__ float lp [RLZ*RLX];           // 48 KB: all p rows
    __shared__ float lvz[RLZ*RLX];           // 48 KB: all vz rows
    // total 96 KB -> 1 WG/CU (2x96 > 160), co-residency for the barrier

    const int tid  = threadIdx.x;
    const int xg   = tid & 31;
    const int zblk = tid >> 5;               // 0..31
    const int zb0  = zblk * ZB;
    const int xo   = xg * 4;

    const int wg  = blockIdx.x;
    const int xcd = wg & 7;
    const int ii  = wg >> 3;
    const int s   = ii >> 4;
    const int loc = ii & 15;
    const int tz0 = ((xcd >> 1) * 4 + (loc >> 2)) * TZ;
    const int tx0 = ((xcd & 1) * 4 + (loc & 3)) * TX;
    const int bf  = *(const int*)(ws + FLAG_OFF);
    unsigned* bar = (unsigned*)(ws + BAR_OFF);

    const int rxv = (tid < Rd) ? rxp[tid] : 0;
    const int rzv = (tid < Rd) ? rzp[tid] : -1000;
    const bool own = (tid < Rd) && (rzv >= tz0 && rzv < tz0 + TZ &&
                                    rxv >= tx0 && rxv < tx0 + TX);
    const int lrcv = (rzv - tz0 + Hz) * RLX + (rxv - tx0 + Hx);
    const int sxv = sxp[s], szv = szp[s];

    // clamped cross-block row indices (region edges tolerate garbage)
    const int zPm  = (zb0 - 1 < 0) ? 0 : zb0 - 1;
    const int zPn0 = (zb0 + ZB     > RLZ - 1) ? RLZ - 1 : zb0 + ZB;
    const int zPn1 = (zb0 + ZB + 1 > RLZ - 1) ? RLZ - 1 : zb0 + ZB + 1;
    const int zVm2 = (zb0 - 2 < 0) ? 0 : zb0 - 2;
    const int zVm1 = zPm;
    const int zVn0 = zPn0;

    const float4 zero4 = {0.f, 0.f, 0.f, 0.f};

    // ---- coefficients: loaded once, register-resident for the whole run
    float4 Ca[ZB], Cb[ZB], Cq[ZB];
    #pragma unroll
    for (int r = 0; r < ZB; ++r) {
        int gz = tz0 - Hz + zb0 + r;
        int gx = tx0 - Hx + xo;
        float4 a = zero4, b = zero4, q = zero4;
        if (gz >= 0 && gz < NZd) {
            #pragma unroll
            for (int c = 0; c < 4; ++c) {
                int x = gx + c;
                if (x >= 0 && x < NXd) {
                    int gi = gz * NXd + x;
                    float v  = load_in(vp,  gi, bf);
                    float rr = load_in(rho, gi, bf);
                    float d  = load_in(damp, gi, bf);
                    ((float*)&a)[c] = d;
                    ((float*)&b)[c] = d * (CVXf / rr);
                    ((float*)&q)[c] = d * (CVXf * rr * v * v);
                }
            }
        }
        Ca[r] = a; Cb[r] = b; Cq[r] = q;
    }

    float4 Pv[ZB], Vx[ZB], Vz[ZB];
    #pragma unroll
    for (int r = 0; r < ZB; ++r) { Pv[r] = zero4; Vx[r] = zero4; Vz[r] = zero4; }

    for (int w = 0; w < NWIN; ++w) {
        const int kk = (NTd - w * KSTEPS < KSTEPS) ? (NTd - w * KSTEPS) : KSTEPS;
        const float* bR = ws + (w & 1) * BUF_SZ;
        float*       bW = ws + ((w + 1) & 1) * BUF_SZ;
        const float* rp  = bR + s * NN;
        const float* rvx = bR + FSZ + s * NN;
        const float* rvz = bR + 2 * FSZ + s * NN;

        // ---- halo refresh (tile interior stays in registers) + lp fill
        #pragma unroll
        for (int r = 0; r < ZB; ++r) {
            int z = zb0 + r;
            int gz = tz0 - Hz + z;
            int gx = tx0 - Hx + xo;
            bool intile = (z >= Hz && z < Hz + TZ && xo >= Hx && xo < Hx + TX);
            if (!intile) {
                bool in = (gz >= 0) && (gz < NZd) && (gx >= 0) && (gx < NXd);
                if (in) {
                    int gi = gz * NXd + gx;
                    Pv[r] = ld4(rp + gi); Vx[r] = ld4(rvx + gi); Vz[r] = ld4(rvz + gi);
                } else {
                    Pv[r] = zero4; Vx[r] = zero4; Vz[r] = zero4;
                }
            }
            st4(lp + z * RLX + xo, Pv[r]);
        }
        __syncthreads();

        for (int j = 0; j < kk; ++j) {
            const int t = w * KSTEPS + j;
            const float wv = (bf ? __bfloat162float(((const __hip_bfloat16*)wav)[s*NTd + t])
                                 : ((const float*)wav)[s*NTd + t]) * SRC_AMPf;

            const int mV = 4 * (kk - 1 - j) + 2;
            const int mP = mV - 2;
            const bool actV = (zb0 + ZB > Hz - mV) && (zb0 < Hz + TZ + mV);
            const bool actP = (zb0 + ZB > Hz - mP) && (zb0 < Hz + TZ + mP);

            // ---------- V phase: vx,vz <- A*v + B*df(p)
            if (actV) {
                float4 pPm  = ld4(lp + zPm  * RLX + xo);
                float4 pNx0 = ld4(lp + zPn0 * RLX + xo);
                float4 pNx1 = ld4(lp + zPn1 * RLX + xo);
                #pragma unroll
                for (int r = 0; r < ZB; ++r) {
                    float4 c = Pv[r];
                    float pmw = sh_up1(c.w);
                    float ppx = sh_dn1(c.x);
                    float ppy = sh_dn1(c.y);
                    float4 pzm = (r == 0) ? pPm : Pv[(r == 0) ? 0 : r - 1];
                    float4 pz1 = (r == ZB-1) ? pNx0 : Pv[(r == ZB-1) ? ZB-1 : r + 1];
                    float4 pz2 = (r == ZB-2) ? pNx0 : ((r == ZB-1) ? pNx1 : Pv[(r >= ZB-2) ? ZB-1 : r + 2]);
                    float4 dfx, dfz;
                    dfx.x = C1f*(c.y - c.x) + C2f*(c.z - pmw);
                    dfx.y = C1f*(c.z - c.y) + C2f*(c.w - c.x);
                    dfx.z = C1f*(c.w - c.z) + C2f*(ppx - c.y);
                    dfx.w = C1f*(ppx - c.w) + C2f*(ppy - c.z);
                    dfz.x = C1f*(pz1.x - c.x) + C2f*(pz2.x - pzm.x);
                    dfz.y = C1f*(pz1.y - c.y) + C2f*(pz2.y - pzm.y);
                    dfz.z = C1f*(pz1.z - c.z) + C2f*(pz2.z - pzm.z);
                    dfz.w = C1f*(pz1.w - c.w) + C2f*(pz2.w - pzm.w);
                    Vx[r].x = Ca[r].x*Vx[r].x + Cb[r].x*dfx.x;
                    Vx[r].y = Ca[r].y*Vx[r].y + Cb[r].y*dfx.y;
                    Vx[r].z = Ca[r].z*Vx[r].z + Cb[r].z*dfx.z;
                    Vx[r].w = Ca[r].w*Vx[r].w + Cb[r].w*dfx.w;
                    Vz[r].x = Ca[r].x*Vz[r].x + Cb[r].x*dfz.x;
                    Vz[r].y = Ca[r].y*Vz[r].y + Cb[r].y*dfz.y;
                    Vz[r].z = Ca[r].z*Vz[r].z + Cb[r].z*dfz.z;
                    Vz[r].w = Ca[r].w*Vz[r].w + Cb[r].w*dfz.w;
                    st4(lvz + (zb0 + r) * RLX + xo, Vz[r]);
                }
            }
            __syncthreads();

            // ---------- P phase: p <- A*p + Q*(dbx(vx)+dbz(vz)) [+ source]
            if (actP) {
                float4 vm2 = ld4(lvz + zVm2 * RLX + xo);
                float4 vm1 = ld4(lvz + zVm1 * RLX + xo);
                float4 vn0 = ld4(lvz + zVn0 * RLX + xo);
                #pragma unroll
                for (int r = 0; r < ZB; ++r) {
                    float4 cx = Vx[r], cz = Vz[r];
                    float vmz = sh_up1(cx.z);
                    float vmw = sh_up1(cx.w);
                    float vpx = sh_dn1(cx.x);
                    float4 zm2 = (r == 0) ? vm2 : ((r == 1) ? vm1 : Vz[(r >= 2) ? r - 2 : 0]);
                    float4 zm1 = (r == 0) ? vm1 : Vz[(r == 0) ? 0 : r - 1];
                    float4 zp1 = (r == ZB-1) ? vn0 : Vz[(r == ZB-1) ? ZB-1 : r + 1];
                    float4 dbx, dbz;
                    dbx.x = C1f*(cx.x - vmw)  + C2f*(cx.y - vmz);
                    dbx.y = C1f*(cx.y - cx.x) + C2f*(cx.z - vmw);
                    dbx.z = C1f*(cx.z - cx.y) + C2f*(cx.w - cx.x);
                    dbx.w = C1f*(cx.w - cx.z) + C2f*(vpx  - cx.y);
                    dbz.x = C1f*(cz.x - zm1.x) + C2f*(zp1.x - zm2.x);
                    dbz.y = C1f*(cz.y - zm1.y) + C2f*(zp1.y - zm2.y);
                    dbz.z = C1f*(cz.z - zm1.z) + C2f*(zp1.z - zm2.z);
                    dbz.w = C1f*(cz.w - zm1.w) + C2f*(zp1.w - zm2.w);
                    Pv[r].x = Ca[r].x*Pv[r].x + Cq[r].x*(dbx.x + dbz.x);
                    Pv[r].y = Ca[r].y*Pv[r].y + Cq[r].y*(dbx.y + dbz.y);
                    Pv[r].z = Ca[r].z*Pv[r].z + Cq[r].z*(dbx.z + dbz.z);
                    Pv[r].w = Ca[r].w*Pv[r].w + Cq[r].w*(dbx.w + dbz.w);
                    int gz = tz0 - Hz + zb0 + r;
                    if (gz == szv) {
                        int dcol = sxv - (tx0 - Hx + xo);
                        if      (dcol == 0) Pv[r].x += wv;
                        else if (dcol == 1) Pv[r].y += wv;
                        else if (dcol == 2) Pv[r].z += wv;
                        else if (dcol == 3) Pv[r].w += wv;
                    }
                    st4(lp + (zb0 + r) * RLX + xo, Pv[r]);
                }
            }
            __syncthreads();

            if (own) {
                float val = lp[lrcv];
                int oi = (s * NTd + t) * Rd + tid;
                if (bf) {
                    __hip_bfloat16 h = __float2bfloat16(val);
                    unsigned short bits; __builtin_memcpy(&bits, &h, 2);
                    sth_wt((__hip_bfloat16*)out + oi, bits);
                } else {
                    st1_wt((float*)out + oi, val);
                }
            }
        }

        // ---- publish tile interior (write-through: no dirty L2 at barrier)
        float* wp  = bW + s * NN;
        float* wvx = bW + FSZ + s * NN;
        float* wvz = bW + 2 * FSZ + s * NN;
        #pragma unroll
        for (int r = 0; r < ZB; ++r) {
            int z = zb0 + r;
            if (z >= Hz && z < Hz + TZ && xo >= Hx && xo < Hx + TX) {
                int gi = (tz0 - Hz + z) * NXd + (tx0 - Hx + xo);
                st4_wt(wp + gi, Pv[r]);
                st4_wt(wvx + gi, Vx[r]);
                st4_wt(wvz + gi, Vz[r]);
            }
        }

        if (w < NWIN - 1) gbar(bar, wg, w);
    }
}

extern "C" void kernel_launch(void* const* d_in, const int* in_sizes, int n_in,
                              void* d_out, int out_size, void* d_ws, size_t ws_size,
                              hipStream_t stream) {
    if (ws_size < WS_NEED_BYTES) return;
    float* ws = (float*)d_ws;
    const void* vp   = d_in[0];
    const void* rho  = d_in[1];
    const void* damp = d_in[2];
    const void* wav  = d_in[3];
    const int* src_x = (const int*)d_in[4];
    const int* src_z = (const int*)d_in[5];
    const int* rcv_x = (const int*)d_in[6];
    const int* rcv_z = (const int*)d_in[7];

    hipMemsetAsync(ws, 0, WS_NEED_BYTES, stream);
    detect_k<<<1, 64, 0, stream>>>((const uint32_t*)vp, (int*)(ws + FLAG_OFF));
    persist_k<<<256, NTHR, 0, stream>>>(ws, d_out, vp, rho, damp, wav,
                                        src_x, src_z, rcv_x, rcv_z);
}